// Round 9
// baseline (224.802 us; speedup 1.0000x reference)
//
#include <hip/hip_runtime.h>

// Problem constants (B=2, W=2048, C=768, H=12, head dim 64)
constexpr int B_  = 2;
constexpr int W_  = 2048;
constexpr int C_  = 768;
constexpr int H_  = 12;
constexpr int HD  = 64;
constexpr int C3  = 3 * C_;           // 2304
constexpr int M_  = B_ * W_;          // 4096
constexpr int NSLOT = 80;             // (qtile,chunk) pairs per (b,h)

typedef float  f32x4 __attribute__((ext_vector_type(4)));
typedef short  s16x8 __attribute__((ext_vector_type(8)));
typedef short  s16x4 __attribute__((ext_vector_type(4)));
typedef unsigned short u16;
typedef unsigned int   u32;

// fp32 -> bf16 (round-to-nearest-even), bit pattern as ushort
__device__ __forceinline__ u16 f2bf(float f) {
    unsigned int u = __float_as_uint(f);
    u += 0x7FFFu + ((u >> 16) & 1u);
    return (u16)(u >> 16);
}

// async global->LDS, 16 bytes per lane. LDS dest = wave-uniform base + lane*16.
__device__ __forceinline__ void gload_lds16(const u16* g, u16* l) {
    __builtin_amdgcn_global_load_lds(
        (const __attribute__((address_space(1))) unsigned int*)g,
        (__attribute__((address_space(3))) unsigned int*)l, 16, 0, 0);
}

// ---------------------------------------------------------------------------
// fp32 -> bf16 bulk convert, all three tensors in one launch (8 elems/thread)
// ---------------------------------------------------------------------------
__global__ __launch_bounds__(256)
void cvt_all(const float* __restrict__ x, const float* __restrict__ wa,
             const float* __restrict__ wp, u16* __restrict__ xb,
             u16* __restrict__ wab, u16* __restrict__ wpb)
{
    const int n0 = M_ * C_ / 8;
    const int n1 = n0 + C3 * C_ / 8;
    const int n2 = n1 + C_ * C_ / 8;
    int i = blockIdx.x * 256 + threadIdx.x;
    const float* s; u16* d; int j;
    if (i < n0)      { s = x;  d = xb;  j = i; }
    else if (i < n1) { s = wa; d = wab; j = i - n0; }
    else if (i < n2) { s = wp; d = wpb; j = i - n1; }
    else return;
    const float4 a = reinterpret_cast<const float4*>(s)[j * 2];
    const float4 b = reinterpret_cast<const float4*>(s)[j * 2 + 1];
    s16x8 v;
    v[0] = (short)f2bf(a.x); v[1] = (short)f2bf(a.y);
    v[2] = (short)f2bf(a.z); v[3] = (short)f2bf(a.w);
    v[4] = (short)f2bf(b.x); v[5] = (short)f2bf(b.y);
    v[6] = (short)f2bf(b.z); v[7] = (short)f2bf(b.w);
    reinterpret_cast<s16x8*>(d)[j] = v;
}

// ---------------------------------------------------------------------------
// bf16 NT GEMM via MFMA (validated round 6): 128x128 tile, BK=64, 4 waves,
// fragment-major LDS, global_load_lds staging.
// ---------------------------------------------------------------------------
__device__ __forceinline__ void store_out(u16*  p, float v) { *p = f2bf(v); }
__device__ __forceinline__ void store_out(float* p, float v) { *p = v; }

template <typename OutT>
__global__ __launch_bounds__(256)
void gemm_nt_mfma(const u16* __restrict__ A, const u16* __restrict__ Bm,
                  OutT* __restrict__ Y, int Ndim, int Kdim)
{
    __shared__ __align__(16) u16 As[128 * 64];   // 16 KiB
    __shared__ __align__(16) u16 Bs[128 * 64];   // 16 KiB

    const int t  = threadIdx.x;
    const int w  = t >> 6;
    const int l  = t & 63;
    const int lg = l >> 4;
    const int ln = l & 15;
    const int wm = w >> 1;
    const int wn = w & 1;
    const int m0 = blockIdx.x * 128;
    const int n0 = blockIdx.y * 128;

    f32x4 acc[4][4];
    #pragma unroll
    for (int mi = 0; mi < 4; ++mi)
        #pragma unroll
        for (int ni = 0; ni < 4; ++ni)
            acc[mi][ni] = (f32x4){0.f, 0.f, 0.f, 0.f};

    for (int k0 = 0; k0 < Kdim; k0 += 64) {
        #pragma unroll
        for (int it = 0; it < 4; ++it) {
            const int c  = t + it * 256;        // chunk 0..1023
            const int fr = c >> 7;
            const int s  = (c >> 6) & 1;
            const int kc = (c >> 4) & 3;
            const int rr = c & 15;
            const size_t koff = (size_t)k0 + s * 32 + kc * 8;
            const u16* ga = A  + (size_t)(m0 + fr * 16 + rr) * Kdim + koff;
            const u16* gb = Bm + (size_t)(n0 + fr * 16 + rr) * Kdim + koff;
            gload_lds16(ga, &As[(size_t)(it * 256 + w * 64) * 8]);
            gload_lds16(gb, &Bs[(size_t)(it * 256 + w * 64) * 8]);
        }
        __syncthreads();

        #pragma unroll
        for (int s = 0; s < 2; ++s) {
            s16x8 af[4], bf[4];
            #pragma unroll
            for (int mi = 0; mi < 4; ++mi)
                af[mi] = *reinterpret_cast<const s16x8*>(
                    &As[(size_t)((wm * 4 + mi) * 128 + s * 64 + lg * 16 + ln) * 8]);
            #pragma unroll
            for (int ni = 0; ni < 4; ++ni)
                bf[ni] = *reinterpret_cast<const s16x8*>(
                    &Bs[(size_t)((wn * 4 + ni) * 128 + s * 64 + lg * 16 + ln) * 8]);
            __builtin_amdgcn_s_setprio(1);
            #pragma unroll
            for (int mi = 0; mi < 4; ++mi)
                #pragma unroll
                for (int ni = 0; ni < 4; ++ni)
                    acc[mi][ni] = __builtin_amdgcn_mfma_f32_16x16x32_bf16(
                        af[mi], bf[ni], acc[mi][ni], 0, 0, 0);
            __builtin_amdgcn_s_setprio(0);
        }
        __syncthreads();
    }

    #pragma unroll
    for (int mi = 0; mi < 4; ++mi) {
        const int row = m0 + wm * 64 + mi * 16 + lg * 4;
        #pragma unroll
        for (int ni = 0; ni < 4; ++ni) {
            const int col = n0 + wn * 64 + ni * 16 + ln;
            #pragma unroll
            for (int r = 0; r < 4; ++r)
                store_out(&Y[(size_t)(row + r) * Ndim + col], acc[mi][ni][r]);
        }
    }
}

// ---------------------------------------------------------------------------
// KV-split MFMA causal flash attention, partial pass, v5:
//  - K fragments loaded DIRECTLY from global (L2-resident 256KB/head working
//    set; per-lane 16B contiguous, per-tile pointer hoisted -> ~0 VALU/load).
//    No K LDS staging, no K bank conflicts, 8 KiB LDS saved.
//  - V^T double-buffered in LDS (18.4 KiB total), ONE barrier per tile:
//    sync -> issue vr(g+1) global loads -> compute(cur) -> write vr->cur^1.
//  - 8 blocks/CU target (__launch_bounds__(256,8), VGPR<=64).
//  - swapped QK^T, lane-local P, cvt_pk packing, mask-free fast path
//    (all validated rounds 7-8). Scalar lsum + 2 epilogue shuffles.
// Fixed-shift softmax p=exp2(s*c1-c2); partials combine by pure addition.
// ---------------------------------------------------------------------------
__global__ __launch_bounds__(256, 8)
void attn_partial(const u16* __restrict__ qkv, float* __restrict__ po,
                  float* __restrict__ pl)
{
    __shared__ __align__(16) unsigned char VtB[2][64 * 144];   // 18 KiB

    const int t  = threadIdx.x;
    const int w  = t >> 6;
    const int l  = t & 63;
    const int lg = l >> 4;
    const int ln = l & 15;
    const int p  = blockIdx.x;
    const int h  = blockIdx.y;
    const int b  = blockIdx.z;

    int qt, ck;
    if (p < 8)       { qt = p;                 ck = 0; }
    else if (p < 24) { qt = 8  + ((p - 8) >> 1);  ck = (p - 8) & 1; }
    else if (p < 48) { qt = 16 + (p - 24) / 3;    ck = (p - 24) % 3; }
    else             { qt = 24 + ((p - 48) >> 2); ck = (p - 48) & 3; }

    const int qb  = qt * 64;
    const int q0w = qb + w * 16;
    const int g0  = ck * 8;                     // first 64-key tile
    const int g1  = min(qt + 1, g0 + 8);        // one past last tile
    const int slot = (b * H_ + h) * NSLOT + p;

    const u16* base  = qkv + (size_t)(b * W_) * C3;
    const u16* kbase = base + C_ + h * HD;
    const u16* vbase = base + 2 * C_ + h * HD;

    // Hoisted Q fragments (B operand: col = ln -> q = q0w + ln)
    s16x8 qf[2];
    {
        const u16* qrow = base + (size_t)(q0w + ln) * C3 + h * HD;
        #pragma unroll
        for (int kc = 0; kc < 2; ++kc)
            qf[kc] = *reinterpret_cast<const s16x8*>(&qrow[kc * 32 + lg * 8]);
    }

    // per-lane K base: key row offset ln, dim lg*8 (A-fragment source)
    const u16* kln = kbase + (size_t)ln * C3 + lg * 8;

    f32x4 o[4];
    #pragma unroll
    for (int i = 0; i < 4; ++i) o[i] = (f32x4){0.f, 0.f, 0.f, 0.f};
    float lsum = 0.0f;

    const float c1 = 0.18033688011112042f;   // (1/8) * log2(e)
    const float c2 = 17.312340490667562f;    // 12  * log2(e)

    // V staging decomposition (tile-invariant)
    const int sv_kq  = t >> 4;             // key quad 0..15
    const int sv_d4  = (t & 15) * 4;       // dim 0..60
    const int sv_pos = ((sv_kq >> 3) << 5) + ((sv_kq & 3) << 3)
                     + (((sv_kq >> 2) & 1) << 2);

    s16x4 vr[4];

    // prologue: load + write tile g0's V into buffer 0
    {
        const u16* vsrc = vbase + (size_t)(g0 * 64 + sv_kq * 4) * C3 + sv_d4;
        #pragma unroll
        for (int j = 0; j < 4; ++j)
            vr[j] = *reinterpret_cast<const s16x4*>(&vsrc[(size_t)j * C3]);
        #pragma unroll
        for (int j = 0; j < 4; ++j) {
            s16x4 pk = { vr[0][j], vr[1][j], vr[2][j], vr[3][j] };
            *reinterpret_cast<s16x4*>(VtB[0] + (sv_d4 + j) * 144 + sv_pos * 2) = pk;
        }
    }

    int cur = 0;
    for (int g = g0; g < g1; ++g) {
        const int s0 = g * 64;
        const bool pf = (g + 1 < g1);

        __syncthreads();   // VtB[cur] written; prev compute done

        // issue next tile's V loads (in flight during compute)
        if (pf) {
            const u16* vsrc = vbase + (size_t)(s0 + 64 + sv_kq * 4) * C3 + sv_d4;
            #pragma unroll
            for (int j = 0; j < 4; ++j)
                vr[j] = *reinterpret_cast<const s16x4*>(&vsrc[(size_t)j * C3]);
        }

        const u16* kp = kln + (size_t)s0 * C3;
        const unsigned char* Vc = VtB[cur];

        #pragma unroll
        for (int c = 0; c < 2; ++c) {
            if (s0 + c * 32 <= q0w + 15) {       // wave-uniform causal gate
                float pt[2][4];
                #pragma unroll
                for (int n2 = 0; n2 < 2; ++n2) {
                    // K A-fragments straight from global (L2-hot)
                    const u16* kpS = kp + (size_t)(c * 32 + n2 * 16) * C3;
                    s16x8 kf0 = *reinterpret_cast<const s16x8*>(kpS);
                    s16x8 kf1 = *reinterpret_cast<const s16x8*>(kpS + 32);
                    f32x4 s = (f32x4){0.f, 0.f, 0.f, 0.f};
                    __builtin_amdgcn_s_setprio(1);
                    s = __builtin_amdgcn_mfma_f32_16x16x32_bf16(kf0, qf[0], s, 0, 0, 0);
                    s = __builtin_amdgcn_mfma_f32_16x16x32_bf16(kf1, qf[1], s, 0, 0, 0);
                    __builtin_amdgcn_s_setprio(0);
                    // lane (lg,ln): keys s0+c*32+n2*16+lg*4+r, col q = q0w+ln
                    const int kg0   = s0 + c * 32 + n2 * 16 + lg * 4;
                    const int klast = s0 + c * 32 + n2 * 16 + 15;
                    if (klast <= q0w) {
                        #pragma unroll
                        for (int r = 0; r < 4; ++r)
                            pt[n2][r] = exp2f(fmaf(s[r], c1, -c2));
                    } else {
                        const int qg = q0w + ln;
                        #pragma unroll
                        for (int r = 0; r < 4; ++r)
                            pt[n2][r] = (kg0 + r <= qg)
                                      ? exp2f(fmaf(s[r], c1, -c2)) : 0.0f;
                    }
                }
                #pragma unroll
                for (int r = 0; r < 4; ++r)
                    lsum += pt[0][r] + pt[1][r];
                // pack lane-local A-fragment via cvt_pk (lo = src0)
                union { s16x8 v; u32 wd[4]; } afu;
                asm("v_cvt_pk_bf16_f32 %0, %1, %2"
                    : "=v"(afu.wd[0]) : "v"(pt[0][0]), "v"(pt[0][1]));
                asm("v_cvt_pk_bf16_f32 %0, %1, %2"
                    : "=v"(afu.wd[1]) : "v"(pt[0][2]), "v"(pt[0][3]));
                asm("v_cvt_pk_bf16_f32 %0, %1, %2"
                    : "=v"(afu.wd[2]) : "v"(pt[1][0]), "v"(pt[1][1]));
                asm("v_cvt_pk_bf16_f32 %0, %1, %2"
                    : "=v"(afu.wd[3]) : "v"(pt[1][2]), "v"(pt[1][3]));
                const s16x8 af = afu.v;
                // PV: B = permuted V^T from LDS
                s16x8 vf[4];
                #pragma unroll
                for (int dt = 0; dt < 4; ++dt)
                    vf[dt] = *reinterpret_cast<const s16x8*>(
                        Vc + (dt * 16 + ln) * 144 + c * 64 + lg * 16);
                __builtin_amdgcn_s_setprio(1);
                #pragma unroll
                for (int dt = 0; dt < 4; ++dt)
                    o[dt] = __builtin_amdgcn_mfma_f32_16x16x32_bf16(af, vf[dt], o[dt], 0, 0, 0);
                __builtin_amdgcn_s_setprio(0);
            }
        }

        // write prefetched V to the other buffer
        if (pf) {
            #pragma unroll
            for (int j = 0; j < 4; ++j) {
                s16x4 pk = { vr[0][j], vr[1][j], vr[2][j], vr[3][j] };
                *reinterpret_cast<s16x4*>(
                    VtB[cur ^ 1] + (sv_d4 + j) * 144 + sv_pos * 2) = pk;
            }
        }
        cur ^= 1;
    }

    // ---- epilogue ----
    // lsum is per-lane (q = ln); reduce across the 4 lg groups
    {
        float v = lsum;
        v += __shfl_xor(v, 16);
        v += __shfl_xor(v, 32);
        if (lg == 0) pl[(size_t)slot * 64 + w * 16 + ln] = v;
    }
    // o layout: lane (lg,ln) holds q = lg*4+r, dim = dt*16+ln
    float* os = po + (size_t)slot * 4096;
    #pragma unroll
    for (int r = 0; r < 4; ++r)
        #pragma unroll
        for (int dt = 0; dt < 4; ++dt)
            os[(w * 16 + lg * 4 + r) * 64 + dt * 16 + ln] = o[dt][r];
}

// ---------------------------------------------------------------------------
// Combine pass: per (qtile,h,b), sum <=4 chunk partials, normalize, emit bf16.
// ---------------------------------------------------------------------------
__global__ __launch_bounds__(256)
void attn_combine(const float* __restrict__ po, const float* __restrict__ pl,
                  u16* __restrict__ aob)
{
    const int qt = blockIdx.x;
    const int h  = blockIdx.y;
    const int b  = blockIdx.z;
    const int nc = (qt + 8) >> 3;               // ceil((qt+1)/8)
    int cum;
    if (qt < 8)       cum = qt;
    else if (qt < 16) cum = 8  + 2 * (qt - 8);
    else if (qt < 24) cum = 24 + 3 * (qt - 16);
    else              cum = 48 + 4 * (qt - 24);
    const int slot0 = (b * H_ + h) * NSLOT + cum;

    const int tid = threadIdx.x;
    const int i   = tid >> 2;          // query row in tile (0..63)
    const int d0  = (tid & 3) * 16;    // dim start (16 dims per thread)

    f32x4 acc[4] = { (f32x4){0,0,0,0}, (f32x4){0,0,0,0},
                     (f32x4){0,0,0,0}, (f32x4){0,0,0,0} };
    float lt = 0.0f;
    for (int c = 0; c < nc; ++c) {
        const float* os = po + (size_t)(slot0 + c) * 4096 + i * 64 + d0;
        #pragma unroll
        for (int v = 0; v < 4; ++v)
            acc[v] += *reinterpret_cast<const f32x4*>(os + v * 4);
        lt += pl[(size_t)(slot0 + c) * 64 + i];
    }
    const float inv = 1.0f / lt;

    u16* dst = aob + (size_t)(b * W_ + qt * 64 + i) * C_ + h * HD + d0;
    s16x8 ov[2];
    #pragma unroll
    for (int v = 0; v < 4; ++v)
        #pragma unroll
        for (int e = 0; e < 4; ++e)
            ov[v >> 1][(v & 1) * 4 + e] = (short)f2bf(acc[v][e] * inv);
    *reinterpret_cast<s16x8*>(dst)     = ov[0];
    *reinterpret_cast<s16x8*>(dst + 8) = ov[1];
}

// ---------------------------------------------------------------------------
extern "C" void kernel_launch(void* const* d_in, const int* in_sizes, int n_in,
                              void* d_out, int out_size, void* d_ws, size_t ws_size,
                              hipStream_t stream)
{
    const float* x      = (const float*)d_in[0];  // [B,W,C]
    const float* w_attn = (const float*)d_in[1];  // [3C,C]
    const float* w_proj = (const float*)d_in[2];  // [C,C]
    float* out = (float*)d_out;                   // [B,W,C]

    u16* xb   = (u16*)d_ws;                       // [M,  C]
    u16* wab  = xb   + (size_t)M_ * C_;           // [3C, C]
    u16* wpb  = wab  + (size_t)C3 * C_;           // [C,  C]
    u16* qkvb = wpb  + (size_t)C_ * C_;           // [M, 3C]
    u16* aob  = qkvb + (size_t)M_ * C3;           // [M,  C]
    float* po = (float*)(aob + (size_t)M_ * C_);  // partials o
    float* pl = po + (size_t)B_ * H_ * NSLOT * 4096;  // partials l

    // 0) fp32 -> bf16 conversions (single launch)
    {
        const int total8 = (M_ * C_ + C3 * C_ + C_ * C_) / 8;
        cvt_all<<<(total8 + 255) / 256, 256, 0, stream>>>(
            x, w_attn, w_proj, xb, wab, wpb);
    }

    // 1) QKV projection (bf16 MFMA, BK=64): qkvb = xb @ wab^T
    {
        dim3 grid(M_ / 128, C3 / 128);
        gemm_nt_mfma<u16><<<grid, 256, 0, stream>>>(xb, wab, qkvb, C3, C_);
    }

    // 2a) KV-split attention partials (1920 blocks, K-from-global, V dbuf)
    {
        dim3 grid(NSLOT, H_, B_);
        attn_partial<<<grid, 256, 0, stream>>>(qkvb, po, pl);
    }
    // 2b) combine + normalize
    {
        dim3 grid(W_ / 64, H_, B_);
        attn_combine<<<grid, 256, 0, stream>>>(po, pl, aob);
    }

    // 3) Output projection (bf16 MFMA, fp32 out): out = aob @ wpb^T
    {
        dim3 grid(M_ / 128, C_ / 128);
        gemm_nt_mfma<float><<<grid, 256, 0, stream>>>(aob, wpb, out, C_, C_);
    }
}

// Round 10
// 127.501 us; speedup vs baseline: 1.7631x; 1.7631x over previous
//
#include <hip/hip_runtime.h>

// Problem constants (B=2, W=2048, C=768, H=12, head dim 64)
constexpr int B_  = 2;
constexpr int W_  = 2048;
constexpr int C_  = 768;
constexpr int H_  = 12;
constexpr int HD  = 64;
constexpr int C3  = 3 * C_;           // 2304
constexpr int M_  = B_ * W_;          // 4096
constexpr int NSLOT = 80;             // (qtile,chunk) pairs per (b,h)

typedef float  f32x4 __attribute__((ext_vector_type(4)));
typedef short  s16x8 __attribute__((ext_vector_type(8)));
typedef short  s16x4 __attribute__((ext_vector_type(4)));
typedef unsigned short u16;
typedef unsigned int   u32;

// fp32 -> bf16 (round-to-nearest-even), bit pattern as ushort
__device__ __forceinline__ u16 f2bf(float f) {
    unsigned int u = __float_as_uint(f);
    u += 0x7FFFu + ((u >> 16) & 1u);
    return (u16)(u >> 16);
}

// async global->LDS, 16 bytes per lane. LDS dest = wave-uniform base + lane*16.
__device__ __forceinline__ void gload_lds16(const u16* g, u16* l) {
    __builtin_amdgcn_global_load_lds(
        (const __attribute__((address_space(1))) unsigned int*)g,
        (__attribute__((address_space(3))) unsigned int*)l, 16, 0, 0);
}

// ---------------------------------------------------------------------------
// fp32 -> bf16 bulk convert, all three tensors in one launch (8 elems/thread)
// ---------------------------------------------------------------------------
__global__ __launch_bounds__(256)
void cvt_all(const float* __restrict__ x, const float* __restrict__ wa,
             const float* __restrict__ wp, u16* __restrict__ xb,
             u16* __restrict__ wab, u16* __restrict__ wpb)
{
    const int n0 = M_ * C_ / 8;
    const int n1 = n0 + C3 * C_ / 8;
    const int n2 = n1 + C_ * C_ / 8;
    int i = blockIdx.x * 256 + threadIdx.x;
    const float* s; u16* d; int j;
    if (i < n0)      { s = x;  d = xb;  j = i; }
    else if (i < n1) { s = wa; d = wab; j = i - n0; }
    else if (i < n2) { s = wp; d = wpb; j = i - n1; }
    else return;
    const float4 a = reinterpret_cast<const float4*>(s)[j * 2];
    const float4 b = reinterpret_cast<const float4*>(s)[j * 2 + 1];
    s16x8 v;
    v[0] = (short)f2bf(a.x); v[1] = (short)f2bf(a.y);
    v[2] = (short)f2bf(a.z); v[3] = (short)f2bf(a.w);
    v[4] = (short)f2bf(b.x); v[5] = (short)f2bf(b.y);
    v[6] = (short)f2bf(b.z); v[7] = (short)f2bf(b.w);
    reinterpret_cast<s16x8*>(d)[j] = v;
}

// ---------------------------------------------------------------------------
// bf16 NT GEMM via MFMA (validated round 6): 128x128 tile, BK=64, 4 waves,
// fragment-major LDS, global_load_lds staging.
// ---------------------------------------------------------------------------
__device__ __forceinline__ void store_out(u16*  p, float v) { *p = f2bf(v); }
__device__ __forceinline__ void store_out(float* p, float v) { *p = v; }

template <typename OutT>
__global__ __launch_bounds__(256)
void gemm_nt_mfma(const u16* __restrict__ A, const u16* __restrict__ Bm,
                  OutT* __restrict__ Y, int Ndim, int Kdim)
{
    __shared__ __align__(16) u16 As[128 * 64];   // 16 KiB
    __shared__ __align__(16) u16 Bs[128 * 64];   // 16 KiB

    const int t  = threadIdx.x;
    const int w  = t >> 6;
    const int l  = t & 63;
    const int lg = l >> 4;
    const int ln = l & 15;
    const int wm = w >> 1;
    const int wn = w & 1;
    const int m0 = blockIdx.x * 128;
    const int n0 = blockIdx.y * 128;

    f32x4 acc[4][4];
    #pragma unroll
    for (int mi = 0; mi < 4; ++mi)
        #pragma unroll
        for (int ni = 0; ni < 4; ++ni)
            acc[mi][ni] = (f32x4){0.f, 0.f, 0.f, 0.f};

    for (int k0 = 0; k0 < Kdim; k0 += 64) {
        #pragma unroll
        for (int it = 0; it < 4; ++it) {
            const int c  = t + it * 256;        // chunk 0..1023
            const int fr = c >> 7;
            const int s  = (c >> 6) & 1;
            const int kc = (c >> 4) & 3;
            const int rr = c & 15;
            const size_t koff = (size_t)k0 + s * 32 + kc * 8;
            const u16* ga = A  + (size_t)(m0 + fr * 16 + rr) * Kdim + koff;
            const u16* gb = Bm + (size_t)(n0 + fr * 16 + rr) * Kdim + koff;
            gload_lds16(ga, &As[(size_t)(it * 256 + w * 64) * 8]);
            gload_lds16(gb, &Bs[(size_t)(it * 256 + w * 64) * 8]);
        }
        __syncthreads();

        #pragma unroll
        for (int s = 0; s < 2; ++s) {
            s16x8 af[4], bf[4];
            #pragma unroll
            for (int mi = 0; mi < 4; ++mi)
                af[mi] = *reinterpret_cast<const s16x8*>(
                    &As[(size_t)((wm * 4 + mi) * 128 + s * 64 + lg * 16 + ln) * 8]);
            #pragma unroll
            for (int ni = 0; ni < 4; ++ni)
                bf[ni] = *reinterpret_cast<const s16x8*>(
                    &Bs[(size_t)((wn * 4 + ni) * 128 + s * 64 + lg * 16 + ln) * 8]);
            __builtin_amdgcn_s_setprio(1);
            #pragma unroll
            for (int mi = 0; mi < 4; ++mi)
                #pragma unroll
                for (int ni = 0; ni < 4; ++ni)
                    acc[mi][ni] = __builtin_amdgcn_mfma_f32_16x16x32_bf16(
                        af[mi], bf[ni], acc[mi][ni], 0, 0, 0);
            __builtin_amdgcn_s_setprio(0);
        }
        __syncthreads();
    }

    #pragma unroll
    for (int mi = 0; mi < 4; ++mi) {
        const int row = m0 + wm * 64 + mi * 16 + lg * 4;
        #pragma unroll
        for (int ni = 0; ni < 4; ++ni) {
            const int col = n0 + wn * 64 + ni * 16 + ln;
            #pragma unroll
            for (int r = 0; r < 4; ++r)
                store_out(&Y[(size_t)(row + r) * Ndim + col], acc[mi][ni][r]);
        }
    }
}

// ---------------------------------------------------------------------------
// KV-split MFMA causal flash attention, partial pass, v6 (= round-8 v4 body
// with conflict-free V staging):
//  - K LDS staged, XOR-swizzled (conflict-free; ablation-verified round 9).
//  - V^T staging re-decomposed: 128 threads x (8 keys x 4 dims), writing
//    4 x ds_write_b128 per thread. Banks = 16(dq&1)+4j+4run -> uniform
//    8 words/bank = b128 hardware minimum -> zero excess conflicts.
//    (Was: 256 threads x 4 x b64 -> 8-way conflict, ~7.3M/dispatch.)
//  - swapped QK^T, lane-local P, cvt_pk pack, mask-free fast path,
//    ones-MFMA row-sum (all validated rounds 7-8).
// Fixed-shift softmax p=exp2(s*c1-c2); partials combine by pure addition.
// ---------------------------------------------------------------------------
__global__ __launch_bounds__(256)
void attn_partial(const u16* __restrict__ qkv, float* __restrict__ po,
                  float* __restrict__ pl)
{
    __shared__ __align__(16) unsigned char KsB[64 * 128];       // 8 KiB
    __shared__ __align__(16) unsigned char VtB[64 * 144];       // 9 KiB
    __shared__ __align__(16) unsigned char OnesB[16 * 144];     // 2.25 KiB

    const int t  = threadIdx.x;
    const int w  = t >> 6;
    const int l  = t & 63;
    const int lg = l >> 4;
    const int ln = l & 15;
    const int p  = blockIdx.x;
    const int h  = blockIdx.y;
    const int b  = blockIdx.z;

    // init ones buffer (row 0 = bf16 1.0, rows 1..15 = 0)
    if (t < 576) ((u32*)OnesB)[t] = (t < 36) ? 0x3F803F80u : 0u;

    int qt, ck;
    if (p < 8)       { qt = p;                 ck = 0; }
    else if (p < 24) { qt = 8  + ((p - 8) >> 1);  ck = (p - 8) & 1; }
    else if (p < 48) { qt = 16 + (p - 24) / 3;    ck = (p - 24) % 3; }
    else             { qt = 24 + ((p - 48) >> 2); ck = (p - 48) & 3; }

    const int qb  = qt * 64;
    const int q0w = qb + w * 16;
    const int g0  = ck * 8;                     // first 64-key tile
    const int g1  = min(qt + 1, g0 + 8);        // one past last tile
    const int slot = (b * H_ + h) * NSLOT + p;

    const u16* base  = qkv + (size_t)(b * W_) * C3;
    const u16* kbase = base + C_ + h * HD;
    const u16* vbase = base + 2 * C_ + h * HD;

    // Hoisted Q fragments (B operand: col = ln -> q = q0w + ln)
    s16x8 qf[2];
    {
        const u16* qrow = base + (size_t)(q0w + ln) * C3 + h * HD;
        #pragma unroll
        for (int kc = 0; kc < 2; ++kc)
            qf[kc] = *reinterpret_cast<const s16x8*>(&qrow[kc * 32 + lg * 8]);
    }

    f32x4 o[4];
    #pragma unroll
    for (int i = 0; i < 4; ++i) o[i] = (f32x4){0.f, 0.f, 0.f, 0.f};
    f32x4 o4 = (f32x4){0.f, 0.f, 0.f, 0.f};    // row-sum accumulator (col 0)

    const float c1 = 0.18033688011112042f;   // (1/8) * log2(e)
    const float c2 = 17.312340490667562f;    // 12  * log2(e)

    // K staging decomposition (tile-invariant)
    const int sk_key0 = t >> 3;            // keys t>>3 and t>>3 + 32
    const int sk_d8   = (t & 7) * 8;
    // V staging decomposition: threads 0..127, 8 keys x 4 dims each
    const bool vstage = (t < 128);
    const int vrun = (t >> 4) & 7;         // 0..7 = c*4 + lg
    const int vK0  = (vrun >> 2) * 32 + (vrun & 3) * 4;   // key base
    const int vdq  = (t & 15) * 4;         // dim base

    s16x8 kr[2];
    s16x4 vr[8];

    // prologue: issue loads for tile g0
    {
        const int s0 = g0 * 64;
        kr[0] = *reinterpret_cast<const s16x8*>(
            &kbase[(size_t)(s0 + sk_key0) * C3 + sk_d8]);
        kr[1] = *reinterpret_cast<const s16x8*>(
            &kbase[(size_t)(s0 + sk_key0 + 32) * C3 + sk_d8]);
        if (vstage) {
            const u16* vsrc = vbase + (size_t)(s0 + vK0) * C3 + vdq;
            #pragma unroll
            for (int e = 0; e < 8; ++e)
                vr[e] = *reinterpret_cast<const s16x4*>(
                    &vsrc[(size_t)((e >> 2) * 16 + (e & 3)) * C3]);
        }
    }

    for (int g = g0; g < g1; ++g) {
        const int s0 = g * 64;

        __syncthreads();   // prev compute done -> LDS writable

        // ---- write staged regs to LDS ----
        #pragma unroll
        for (int it = 0; it < 2; ++it) {
            const int key = sk_key0 + it * 32;
            int woff = key * 128 + sk_d8 * 2;
            woff ^= (key & 7) << 4;
            *reinterpret_cast<s16x8*>(KsB + woff) = kr[it];
        }
        if (vstage) {
            #pragma unroll
            for (int j = 0; j < 4; ++j) {
                s16x8 pk = { vr[0][j], vr[1][j], vr[2][j], vr[3][j],
                             vr[4][j], vr[5][j], vr[6][j], vr[7][j] };
                *reinterpret_cast<s16x8*>(
                    VtB + (vdq + j) * 144 + vrun * 16) = pk;
            }
        }

        // ---- issue next tile's global loads (in flight during compute) ----
        if (g + 1 < g1) {
            const int s1 = s0 + 64;
            kr[0] = *reinterpret_cast<const s16x8*>(
                &kbase[(size_t)(s1 + sk_key0) * C3 + sk_d8]);
            kr[1] = *reinterpret_cast<const s16x8*>(
                &kbase[(size_t)(s1 + sk_key0 + 32) * C3 + sk_d8]);
            if (vstage) {
                const u16* vsrc = vbase + (size_t)(s1 + vK0) * C3 + vdq;
                #pragma unroll
                for (int e = 0; e < 8; ++e)
                    vr[e] = *reinterpret_cast<const s16x4*>(
                        &vsrc[(size_t)((e >> 2) * 16 + (e & 3)) * C3]);
            }
        }

        __syncthreads();   // LDS tile ready

        #pragma unroll
        for (int c = 0; c < 2; ++c) {
            if (s0 + c * 32 <= q0w + 15) {       // wave-uniform causal gate
                float pt[2][4];
                #pragma unroll
                for (int n2 = 0; n2 < 2; ++n2) {
                    const int krow = c * 32 + n2 * 16 + ln;   // LDS key row
                    f32x4 s = (f32x4){0.f, 0.f, 0.f, 0.f};
                    s16x8 kf0, kf1;
                    {
                        int r0 = krow * 128 + lg * 16;       r0 ^= (krow & 7) << 4;
                        int r1 = krow * 128 + 64 + lg * 16;  r1 ^= (krow & 7) << 4;
                        kf0 = *reinterpret_cast<const s16x8*>(KsB + r0);
                        kf1 = *reinterpret_cast<const s16x8*>(KsB + r1);
                    }
                    __builtin_amdgcn_s_setprio(1);
                    s = __builtin_amdgcn_mfma_f32_16x16x32_bf16(kf0, qf[0], s, 0, 0, 0);
                    s = __builtin_amdgcn_mfma_f32_16x16x32_bf16(kf1, qf[1], s, 0, 0, 0);
                    __builtin_amdgcn_s_setprio(0);
                    // lane (lg,ln): keys s0+c*32+n2*16+lg*4+r, col q = q0w+ln
                    const int kg0   = s0 + c * 32 + n2 * 16 + lg * 4;
                    const int klast = s0 + c * 32 + n2 * 16 + 15;
                    if (klast <= q0w) {
                        #pragma unroll
                        for (int r = 0; r < 4; ++r)
                            pt[n2][r] = exp2f(fmaf(s[r], c1, -c2));
                    } else {
                        const int qg = q0w + ln;
                        #pragma unroll
                        for (int r = 0; r < 4; ++r)
                            pt[n2][r] = (kg0 + r <= qg)
                                      ? exp2f(fmaf(s[r], c1, -c2)) : 0.0f;
                    }
                }
                // pack lane-local A-fragment via cvt_pk (lo = src0)
                union { s16x8 v; u32 wd[4]; } afu;
                asm("v_cvt_pk_bf16_f32 %0, %1, %2"
                    : "=v"(afu.wd[0]) : "v"(pt[0][0]), "v"(pt[0][1]));
                asm("v_cvt_pk_bf16_f32 %0, %1, %2"
                    : "=v"(afu.wd[1]) : "v"(pt[0][2]), "v"(pt[0][3]));
                asm("v_cvt_pk_bf16_f32 %0, %1, %2"
                    : "=v"(afu.wd[2]) : "v"(pt[1][0]), "v"(pt[1][1]));
                asm("v_cvt_pk_bf16_f32 %0, %1, %2"
                    : "=v"(afu.wd[3]) : "v"(pt[1][2]), "v"(pt[1][3]));
                const s16x8 af = afu.v;
                // PV: B = permuted V^T, one b128 per dt (+ ones row-sum)
                s16x8 vf[4];
                #pragma unroll
                for (int dt = 0; dt < 4; ++dt)
                    vf[dt] = *reinterpret_cast<const s16x8*>(
                        VtB + (dt * 16 + ln) * 144 + c * 64 + lg * 16);
                s16x8 vf4 = *reinterpret_cast<const s16x8*>(
                    OnesB + ln * 144 + c * 64 + lg * 16);
                __builtin_amdgcn_s_setprio(1);
                #pragma unroll
                for (int dt = 0; dt < 4; ++dt)
                    o[dt] = __builtin_amdgcn_mfma_f32_16x16x32_bf16(af, vf[dt], o[dt], 0, 0, 0);
                o4 = __builtin_amdgcn_mfma_f32_16x16x32_bf16(af, vf4, o4, 0, 0, 0);
                __builtin_amdgcn_s_setprio(0);
            }
        }
    }

    // ---- epilogue ----
    // o4 col 0 (lanes ln==0) holds lsum for q = lg*4+r
    if (ln == 0) {
        #pragma unroll
        for (int r = 0; r < 4; ++r)
            pl[(size_t)slot * 64 + w * 16 + lg * 4 + r] = o4[r];
    }
    // o layout: lane (lg,ln) holds q = lg*4+r, dim = dt*16+ln
    float* os = po + (size_t)slot * 4096;
    #pragma unroll
    for (int r = 0; r < 4; ++r)
        #pragma unroll
        for (int dt = 0; dt < 4; ++dt)
            os[(w * 16 + lg * 4 + r) * 64 + dt * 16 + ln] = o[dt][r];
}

// ---------------------------------------------------------------------------
// Combine pass: per (qtile,h,b), sum <=4 chunk partials, normalize, emit bf16.
// ---------------------------------------------------------------------------
__global__ __launch_bounds__(256)
void attn_combine(const float* __restrict__ po, const float* __restrict__ pl,
                  u16* __restrict__ aob)
{
    const int qt = blockIdx.x;
    const int h  = blockIdx.y;
    const int b  = blockIdx.z;
    const int nc = (qt + 8) >> 3;               // ceil((qt+1)/8)
    int cum;
    if (qt < 8)       cum = qt;
    else if (qt < 16) cum = 8  + 2 * (qt - 8);
    else if (qt < 24) cum = 24 + 3 * (qt - 16);
    else              cum = 48 + 4 * (qt - 24);
    const int slot0 = (b * H_ + h) * NSLOT + cum;

    const int tid = threadIdx.x;
    const int i   = tid >> 2;          // query row in tile (0..63)
    const int d0  = (tid & 3) * 16;    // dim start (16 dims per thread)

    f32x4 acc[4] = { (f32x4){0,0,0,0}, (f32x4){0,0,0,0},
                     (f32x4){0,0,0,0}, (f32x4){0,0,0,0} };
    float lt = 0.0f;
    for (int c = 0; c < nc; ++c) {
        const float* os = po + (size_t)(slot0 + c) * 4096 + i * 64 + d0;
        #pragma unroll
        for (int v = 0; v < 4; ++v)
            acc[v] += *reinterpret_cast<const f32x4*>(os + v * 4);
        lt += pl[(size_t)(slot0 + c) * 64 + i];
    }
    const float inv = 1.0f / lt;

    u16* dst = aob + (size_t)(b * W_ + qt * 64 + i) * C_ + h * HD + d0;
    s16x8 ov[2];
    #pragma unroll
    for (int v = 0; v < 4; ++v)
        #pragma unroll
        for (int e = 0; e < 4; ++e)
            ov[v >> 1][(v & 1) * 4 + e] = (short)f2bf(acc[v][e] * inv);
    *reinterpret_cast<s16x8*>(dst)     = ov[0];
    *reinterpret_cast<s16x8*>(dst + 8) = ov[1];
}

// ---------------------------------------------------------------------------
extern "C" void kernel_launch(void* const* d_in, const int* in_sizes, int n_in,
                              void* d_out, int out_size, void* d_ws, size_t ws_size,
                              hipStream_t stream)
{
    const float* x      = (const float*)d_in[0];  // [B,W,C]
    const float* w_attn = (const float*)d_in[1];  // [3C,C]
    const float* w_proj = (const float*)d_in[2];  // [C,C]
    float* out = (float*)d_out;                   // [B,W,C]

    u16* xb   = (u16*)d_ws;                       // [M,  C]
    u16* wab  = xb   + (size_t)M_ * C_;           // [3C, C]
    u16* wpb  = wab  + (size_t)C3 * C_;           // [C,  C]
    u16* qkvb = wpb  + (size_t)C_ * C_;           // [M, 3C]
    u16* aob  = qkvb + (size_t)M_ * C3;           // [M,  C]
    float* po = (float*)(aob + (size_t)M_ * C_);  // partials o
    float* pl = po + (size_t)B_ * H_ * NSLOT * 4096;  // partials l

    // 0) fp32 -> bf16 conversions (single launch)
    {
        const int total8 = (M_ * C_ + C3 * C_ + C_ * C_) / 8;
        cvt_all<<<(total8 + 255) / 256, 256, 0, stream>>>(
            x, w_attn, w_proj, xb, wab, wpb);
    }

    // 1) QKV projection (bf16 MFMA, BK=64): qkvb = xb @ wab^T
    {
        dim3 grid(M_ / 128, C3 / 128);
        gemm_nt_mfma<u16><<<grid, 256, 0, stream>>>(xb, wab, qkvb, C3, C_);
    }

    // 2a) KV-split attention partials (1920 blocks)
    {
        dim3 grid(NSLOT, H_, B_);
        attn_partial<<<grid, 256, 0, stream>>>(qkvb, po, pl);
    }
    // 2b) combine + normalize
    {
        dim3 grid(W_ / 64, H_, B_);
        attn_combine<<<grid, 256, 0, stream>>>(po, pl, aob);
    }

    // 3) Output projection (bf16 MFMA, fp32 out): out = aob @ wpb^T
    {
        dim3 grid(M_ / 128, C_ / 128);
        gemm_nt_mfma<float><<<grid, 256, 0, stream>>>(aob, wpb, out, C_, C_);
    }
}

// Round 11
// 124.570 us; speedup vs baseline: 1.8046x; 1.0235x over previous
//
#include <hip/hip_runtime.h>

// Problem constants (B=2, W=2048, C=768, H=12, head dim 64)
constexpr int B_  = 2;
constexpr int W_  = 2048;
constexpr int C_  = 768;
constexpr int H_  = 12;
constexpr int HD  = 64;
constexpr int C3  = 3 * C_;           // 2304
constexpr int M_  = B_ * W_;          // 4096
constexpr int NSLOT = 80;             // (qtile,chunk) pairs per (b,h)

typedef float  f32x4 __attribute__((ext_vector_type(4)));
typedef short  s16x8 __attribute__((ext_vector_type(8)));
typedef short  s16x4 __attribute__((ext_vector_type(4)));
typedef unsigned short u16;
typedef unsigned int   u32;

// fp32 -> bf16 (round-to-nearest-even), bit pattern as ushort
__device__ __forceinline__ u16 f2bf(float f) {
    unsigned int u = __float_as_uint(f);
    u += 0x7FFFu + ((u >> 16) & 1u);
    return (u16)(u >> 16);
}

// async global->LDS, 16 bytes per lane. LDS dest = wave-uniform base + lane*16.
__device__ __forceinline__ void gload_lds16(const u16* g, u16* l) {
    __builtin_amdgcn_global_load_lds(
        (const __attribute__((address_space(1))) unsigned int*)g,
        (__attribute__((address_space(3))) unsigned int*)l, 16, 0, 0);
}

// ---------------------------------------------------------------------------
// fp32 -> bf16 bulk convert, all three tensors in one launch (8 elems/thread)
// ---------------------------------------------------------------------------
__global__ __launch_bounds__(256)
void cvt_all(const float* __restrict__ x, const float* __restrict__ wa,
             const float* __restrict__ wp, u16* __restrict__ xb,
             u16* __restrict__ wab, u16* __restrict__ wpb)
{
    const int n0 = M_ * C_ / 8;
    const int n1 = n0 + C3 * C_ / 8;
    const int n2 = n1 + C_ * C_ / 8;
    int i = blockIdx.x * 256 + threadIdx.x;
    const float* s; u16* d; int j;
    if (i < n0)      { s = x;  d = xb;  j = i; }
    else if (i < n1) { s = wa; d = wab; j = i - n0; }
    else if (i < n2) { s = wp; d = wpb; j = i - n1; }
    else return;
    const float4 a = reinterpret_cast<const float4*>(s)[j * 2];
    const float4 b = reinterpret_cast<const float4*>(s)[j * 2 + 1];
    s16x8 v;
    v[0] = (short)f2bf(a.x); v[1] = (short)f2bf(a.y);
    v[2] = (short)f2bf(a.z); v[3] = (short)f2bf(a.w);
    v[4] = (short)f2bf(b.x); v[5] = (short)f2bf(b.y);
    v[6] = (short)f2bf(b.z); v[7] = (short)f2bf(b.w);
    reinterpret_cast<s16x8*>(d)[j] = v;
}

// ---------------------------------------------------------------------------
// bf16 NT GEMM via MFMA (validated round 6): 128x128 tile, BK=64, 4 waves,
// fragment-major LDS, global_load_lds staging.
// ---------------------------------------------------------------------------
__device__ __forceinline__ void store_out(u16*  p, float v) { *p = f2bf(v); }
__device__ __forceinline__ void store_out(float* p, float v) { *p = v; }

template <typename OutT>
__global__ __launch_bounds__(256)
void gemm_nt_mfma(const u16* __restrict__ A, const u16* __restrict__ Bm,
                  OutT* __restrict__ Y, int Ndim, int Kdim)
{
    __shared__ __align__(16) u16 As[128 * 64];   // 16 KiB
    __shared__ __align__(16) u16 Bs[128 * 64];   // 16 KiB

    const int t  = threadIdx.x;
    const int w  = t >> 6;
    const int l  = t & 63;
    const int lg = l >> 4;
    const int ln = l & 15;
    const int wm = w >> 1;
    const int wn = w & 1;
    const int m0 = blockIdx.x * 128;
    const int n0 = blockIdx.y * 128;

    f32x4 acc[4][4];
    #pragma unroll
    for (int mi = 0; mi < 4; ++mi)
        #pragma unroll
        for (int ni = 0; ni < 4; ++ni)
            acc[mi][ni] = (f32x4){0.f, 0.f, 0.f, 0.f};

    for (int k0 = 0; k0 < Kdim; k0 += 64) {
        #pragma unroll
        for (int it = 0; it < 4; ++it) {
            const int c  = t + it * 256;        // chunk 0..1023
            const int fr = c >> 7;
            const int s  = (c >> 6) & 1;
            const int kc = (c >> 4) & 3;
            const int rr = c & 15;
            const size_t koff = (size_t)k0 + s * 32 + kc * 8;
            const u16* ga = A  + (size_t)(m0 + fr * 16 + rr) * Kdim + koff;
            const u16* gb = Bm + (size_t)(n0 + fr * 16 + rr) * Kdim + koff;
            gload_lds16(ga, &As[(size_t)(it * 256 + w * 64) * 8]);
            gload_lds16(gb, &Bs[(size_t)(it * 256 + w * 64) * 8]);
        }
        __syncthreads();

        #pragma unroll
        for (int s = 0; s < 2; ++s) {
            s16x8 af[4], bf[4];
            #pragma unroll
            for (int mi = 0; mi < 4; ++mi)
                af[mi] = *reinterpret_cast<const s16x8*>(
                    &As[(size_t)((wm * 4 + mi) * 128 + s * 64 + lg * 16 + ln) * 8]);
            #pragma unroll
            for (int ni = 0; ni < 4; ++ni)
                bf[ni] = *reinterpret_cast<const s16x8*>(
                    &Bs[(size_t)((wn * 4 + ni) * 128 + s * 64 + lg * 16 + ln) * 8]);
            __builtin_amdgcn_s_setprio(1);
            #pragma unroll
            for (int mi = 0; mi < 4; ++mi)
                #pragma unroll
                for (int ni = 0; ni < 4; ++ni)
                    acc[mi][ni] = __builtin_amdgcn_mfma_f32_16x16x32_bf16(
                        af[mi], bf[ni], acc[mi][ni], 0, 0, 0);
            __builtin_amdgcn_s_setprio(0);
        }
        __syncthreads();
    }

    #pragma unroll
    for (int mi = 0; mi < 4; ++mi) {
        const int row = m0 + wm * 64 + mi * 16 + lg * 4;
        #pragma unroll
        for (int ni = 0; ni < 4; ++ni) {
            const int col = n0 + wn * 64 + ni * 16 + ln;
            #pragma unroll
            for (int r = 0; r < 4; ++r)
                store_out(&Y[(size_t)(row + r) * Ndim + col], acc[mi][ni][r]);
        }
    }
}

// ---------------------------------------------------------------------------
// KV-split MFMA causal flash attention, partial pass, v7:
//  - K LDS now FRAGMENT-MAJOR (same trick as the GEMM): chunk
//    cix = frag*64 + lg*16 + ln holds K[keygroup*16+ln][kc*32+lg*8..+8],
//    frag = keygroup*2+kc. Staging writes = KsB + t*16 (wave-contiguous,
//    conflict-free, zero addr math); fragment reads = frag*1024 + lane*16
//    (contiguous 1 KiB, conflict-free). Kills the 8-way K-read conflict of
//    the XOR-swizzled layout (round-10 residual ~3.2M).
//  - ones B-fragment is lane-constant -> register select (OnesB LDS deleted).
//  - V^T staging: 128 threads x (8 keys x 4 dims), 4 x b128, conflict-free
//    (validated round 10). Swapped QK^T, lane-local P, cvt_pk, mask-free
//    fast path, ones-MFMA row-sum (validated rounds 7-10).
// Fixed-shift softmax p=exp2(s*c1-c2); partials combine by pure addition.
// ---------------------------------------------------------------------------
__global__ __launch_bounds__(256)
void attn_partial(const u16* __restrict__ qkv, float* __restrict__ po,
                  float* __restrict__ pl)
{
    __shared__ __align__(16) unsigned char KsB[64 * 128];       // 8 KiB
    __shared__ __align__(16) unsigned char VtB[64 * 144];       // 9 KiB

    const int t  = threadIdx.x;
    const int w  = t >> 6;
    const int l  = t & 63;
    const int lg = l >> 4;
    const int ln = l & 15;
    const int p  = blockIdx.x;
    const int h  = blockIdx.y;
    const int b  = blockIdx.z;

    int qt, ck;
    if (p < 8)       { qt = p;                 ck = 0; }
    else if (p < 24) { qt = 8  + ((p - 8) >> 1);  ck = (p - 8) & 1; }
    else if (p < 48) { qt = 16 + (p - 24) / 3;    ck = (p - 24) % 3; }
    else             { qt = 24 + ((p - 48) >> 2); ck = (p - 48) & 3; }

    const int qb  = qt * 64;
    const int q0w = qb + w * 16;
    const int g0  = ck * 8;                     // first 64-key tile
    const int g1  = min(qt + 1, g0 + 8);        // one past last tile
    const int slot = (b * H_ + h) * NSLOT + p;

    const u16* base  = qkv + (size_t)(b * W_) * C3;
    const u16* kbase = base + C_ + h * HD;
    const u16* vbase = base + 2 * C_ + h * HD;

    // Hoisted Q fragments (B operand: col = ln -> q = q0w + ln)
    s16x8 qf[2];
    {
        const u16* qrow = base + (size_t)(q0w + ln) * C3 + h * HD;
        #pragma unroll
        for (int kc = 0; kc < 2; ++kc)
            qf[kc] = *reinterpret_cast<const s16x8*>(&qrow[kc * 32 + lg * 8]);
    }

    // ones B-fragment in registers: B[k][col=ln] = (ln==0) ? 1 : 0
    s16x8 onesf;
    {
        const short v1 = (ln == 0) ? (short)0x3F80 : (short)0;
        #pragma unroll
        for (int i = 0; i < 8; ++i) onesf[i] = v1;
    }

    f32x4 o[4];
    #pragma unroll
    for (int i = 0; i < 4; ++i) o[i] = (f32x4){0.f, 0.f, 0.f, 0.f};
    f32x4 o4 = (f32x4){0.f, 0.f, 0.f, 0.f};    // row-sum accumulator (col 0)

    const float c1 = 0.18033688011112042f;   // (1/8) * log2(e)
    const float c2 = 17.312340490667562f;    // 12  * log2(e)

    // K staging decomposition (fragment-major): thread t handles chunks
    // t and t+256. chunk cix: keygroup=(cix>>7)&3? -> cix>>7 gives 0..3 over
    // 512 chunks; kc=(cix>>6)&1, lgS=(cix>>4)&3, lnS=cix&15.
    const int sk_kc  = (t >> 6) & 1;
    const int sk_lgS = (t >> 4) & 3;
    const int sk_lnS = t & 15;
    const int sk_kg0 = t >> 7;                 // keygroup of chunk t (0..1)
    const size_t sk_off = (size_t)(sk_kg0 * 16 + sk_lnS) * C3
                        + sk_kc * 32 + sk_lgS * 8;
    // V staging decomposition: threads 0..127, 8 keys x 4 dims each
    const bool vstage = (t < 128);
    const int vrun = (t >> 4) & 7;         // 0..7 = c*4 + lg
    const int vK0  = (vrun >> 2) * 32 + (vrun & 3) * 4;   // key base
    const int vdq  = (t & 15) * 4;         // dim base
    const int kfb  = l * 16;               // lane byte for K fragment reads

    s16x8 kr[2];
    s16x4 vr[8];

    // prologue: issue loads for tile g0
    {
        const int s0 = g0 * 64;
        const u16* ks = kbase + (size_t)s0 * C3 + sk_off;
        kr[0] = *reinterpret_cast<const s16x8*>(ks);
        kr[1] = *reinterpret_cast<const s16x8*>(ks + (size_t)32 * C3);
        if (vstage) {
            const u16* vsrc = vbase + (size_t)(s0 + vK0) * C3 + vdq;
            #pragma unroll
            for (int e = 0; e < 8; ++e)
                vr[e] = *reinterpret_cast<const s16x4*>(
                    &vsrc[(size_t)((e >> 2) * 16 + (e & 3)) * C3]);
        }
    }

    for (int g = g0; g < g1; ++g) {
        const int s0 = g * 64;

        __syncthreads();   // prev compute done -> LDS writable

        // ---- write staged regs to LDS (wave-contiguous, conflict-free) ----
        *reinterpret_cast<s16x8*>(KsB + t * 16)         = kr[0];
        *reinterpret_cast<s16x8*>(KsB + (t + 256) * 16) = kr[1];
        if (vstage) {
            #pragma unroll
            for (int j = 0; j < 4; ++j) {
                s16x8 pk = { vr[0][j], vr[1][j], vr[2][j], vr[3][j],
                             vr[4][j], vr[5][j], vr[6][j], vr[7][j] };
                *reinterpret_cast<s16x8*>(
                    VtB + (vdq + j) * 144 + vrun * 16) = pk;
            }
        }

        // ---- issue next tile's global loads (in flight during compute) ----
        if (g + 1 < g1) {
            const int s1 = s0 + 64;
            const u16* ks = kbase + (size_t)s1 * C3 + sk_off;
            kr[0] = *reinterpret_cast<const s16x8*>(ks);
            kr[1] = *reinterpret_cast<const s16x8*>(ks + (size_t)32 * C3);
            if (vstage) {
                const u16* vsrc = vbase + (size_t)(s1 + vK0) * C3 + vdq;
                #pragma unroll
                for (int e = 0; e < 8; ++e)
                    vr[e] = *reinterpret_cast<const s16x4*>(
                        &vsrc[(size_t)((e >> 2) * 16 + (e & 3)) * C3]);
            }
        }

        __syncthreads();   // LDS tile ready

        #pragma unroll
        for (int c = 0; c < 2; ++c) {
            if (s0 + c * 32 <= q0w + 15) {       // wave-uniform causal gate
                float pt[2][4];
                #pragma unroll
                for (int n2 = 0; n2 < 2; ++n2) {
                    // fragment-major K reads: contiguous 1 KiB per fragment
                    const unsigned char* kfrag = KsB + (c * 2 + n2) * 2048 + kfb;
                    s16x8 kf0 = *reinterpret_cast<const s16x8*>(kfrag);
                    s16x8 kf1 = *reinterpret_cast<const s16x8*>(kfrag + 1024);
                    f32x4 s = (f32x4){0.f, 0.f, 0.f, 0.f};
                    __builtin_amdgcn_s_setprio(1);
                    s = __builtin_amdgcn_mfma_f32_16x16x32_bf16(kf0, qf[0], s, 0, 0, 0);
                    s = __builtin_amdgcn_mfma_f32_16x16x32_bf16(kf1, qf[1], s, 0, 0, 0);
                    __builtin_amdgcn_s_setprio(0);
                    // lane (lg,ln): keys s0+c*32+n2*16+lg*4+r, col q = q0w+ln
                    const int kg0   = s0 + c * 32 + n2 * 16 + lg * 4;
                    const int klast = s0 + c * 32 + n2 * 16 + 15;
                    if (klast <= q0w) {
                        #pragma unroll
                        for (int r = 0; r < 4; ++r)
                            pt[n2][r] = exp2f(fmaf(s[r], c1, -c2));
                    } else {
                        const int qg = q0w + ln;
                        #pragma unroll
                        for (int r = 0; r < 4; ++r)
                            pt[n2][r] = (kg0 + r <= qg)
                                      ? exp2f(fmaf(s[r], c1, -c2)) : 0.0f;
                    }
                }
                // pack lane-local A-fragment via cvt_pk (lo = src0)
                union { s16x8 v; u32 wd[4]; } afu;
                asm("v_cvt_pk_bf16_f32 %0, %1, %2"
                    : "=v"(afu.wd[0]) : "v"(pt[0][0]), "v"(pt[0][1]));
                asm("v_cvt_pk_bf16_f32 %0, %1, %2"
                    : "=v"(afu.wd[1]) : "v"(pt[0][2]), "v"(pt[0][3]));
                asm("v_cvt_pk_bf16_f32 %0, %1, %2"
                    : "=v"(afu.wd[2]) : "v"(pt[1][0]), "v"(pt[1][1]));
                asm("v_cvt_pk_bf16_f32 %0, %1, %2"
                    : "=v"(afu.wd[3]) : "v"(pt[1][2]), "v"(pt[1][3]));
                const s16x8 af = afu.v;
                // PV: B = permuted V^T, one b128 per dt (+ register ones)
                s16x8 vf[4];
                #pragma unroll
                for (int dt = 0; dt < 4; ++dt)
                    vf[dt] = *reinterpret_cast<const s16x8*>(
                        VtB + (dt * 16 + ln) * 144 + c * 64 + lg * 16);
                __builtin_amdgcn_s_setprio(1);
                #pragma unroll
                for (int dt = 0; dt < 4; ++dt)
                    o[dt] = __builtin_amdgcn_mfma_f32_16x16x32_bf16(af, vf[dt], o[dt], 0, 0, 0);
                o4 = __builtin_amdgcn_mfma_f32_16x16x32_bf16(af, onesf, o4, 0, 0, 0);
                __builtin_amdgcn_s_setprio(0);
            }
        }
    }

    // ---- epilogue ----
    // o4 col 0 (lanes ln==0) holds lsum for q = lg*4+r
    if (ln == 0) {
        #pragma unroll
        for (int r = 0; r < 4; ++r)
            pl[(size_t)slot * 64 + w * 16 + lg * 4 + r] = o4[r];
    }
    // o layout: lane (lg,ln) holds q = lg*4+r, dim = dt*16+ln
    float* os = po + (size_t)slot * 4096;
    #pragma unroll
    for (int r = 0; r < 4; ++r)
        #pragma unroll
        for (int dt = 0; dt < 4; ++dt)
            os[(w * 16 + lg * 4 + r) * 64 + dt * 16 + ln] = o[dt][r];
}

// ---------------------------------------------------------------------------
// Combine pass: per (qtile,h,b), sum <=4 chunk partials, normalize, emit bf16.
// ---------------------------------------------------------------------------
__global__ __launch_bounds__(256)
void attn_combine(const float* __restrict__ po, const float* __restrict__ pl,
                  u16* __restrict__ aob)
{
    const int qt = blockIdx.x;
    const int h  = blockIdx.y;
    const int b  = blockIdx.z;
    const int nc = (qt + 8) >> 3;               // ceil((qt+1)/8)
    int cum;
    if (qt < 8)       cum = qt;
    else if (qt < 16) cum = 8  + 2 * (qt - 8);
    else if (qt < 24) cum = 24 + 3 * (qt - 16);
    else              cum = 48 + 4 * (qt - 24);
    const int slot0 = (b * H_ + h) * NSLOT + cum;

    const int tid = threadIdx.x;
    const int i   = tid >> 2;          // query row in tile (0..63)
    const int d0  = (tid & 3) * 16;    // dim start (16 dims per thread)

    f32x4 acc[4] = { (f32x4){0,0,0,0}, (f32x4){0,0,0,0},
                     (f32x4){0,0,0,0}, (f32x4){0,0,0,0} };
    float lt = 0.0f;
    for (int c = 0; c < nc; ++c) {
        const float* os = po + (size_t)(slot0 + c) * 4096 + i * 64 + d0;
        #pragma unroll
        for (int v = 0; v < 4; ++v)
            acc[v] += *reinterpret_cast<const f32x4*>(os + v * 4);
        lt += pl[(size_t)(slot0 + c) * 64 + i];
    }
    const float inv = 1.0f / lt;

    u16* dst = aob + (size_t)(b * W_ + qt * 64 + i) * C_ + h * HD + d0;
    s16x8 ov[2];
    #pragma unroll
    for (int v = 0; v < 4; ++v)
        #pragma unroll
        for (int e = 0; e < 4; ++e)
            ov[v >> 1][(v & 1) * 4 + e] = (short)f2bf(acc[v][e] * inv);
    *reinterpret_cast<s16x8*>(dst)     = ov[0];
    *reinterpret_cast<s16x8*>(dst + 8) = ov[1];
}

// ---------------------------------------------------------------------------
extern "C" void kernel_launch(void* const* d_in, const int* in_sizes, int n_in,
                              void* d_out, int out_size, void* d_ws, size_t ws_size,
                              hipStream_t stream)
{
    const float* x      = (const float*)d_in[0];  // [B,W,C]
    const float* w_attn = (const float*)d_in[1];  // [3C,C]
    const float* w_proj = (const float*)d_in[2];  // [C,C]
    float* out = (float*)d_out;                   // [B,W,C]

    u16* xb   = (u16*)d_ws;                       // [M,  C]
    u16* wab  = xb   + (size_t)M_ * C_;           // [3C, C]
    u16* wpb  = wab  + (size_t)C3 * C_;           // [C,  C]
    u16* qkvb = wpb  + (size_t)C_ * C_;           // [M, 3C]
    u16* aob  = qkvb + (size_t)M_ * C3;           // [M,  C]
    float* po = (float*)(aob + (size_t)M_ * C_);  // partials o
    float* pl = po + (size_t)B_ * H_ * NSLOT * 4096;  // partials l

    // 0) fp32 -> bf16 conversions (single launch)
    {
        const int total8 = (M_ * C_ + C3 * C_ + C_ * C_) / 8;
        cvt_all<<<(total8 + 255) / 256, 256, 0, stream>>>(
            x, w_attn, w_proj, xb, wab, wpb);
    }

    // 1) QKV projection (bf16 MFMA, BK=64): qkvb = xb @ wab^T
    {
        dim3 grid(M_ / 128, C3 / 128);
        gemm_nt_mfma<u16><<<grid, 256, 0, stream>>>(xb, wab, qkvb, C3, C_);
    }

    // 2a) KV-split attention partials (1920 blocks)
    {
        dim3 grid(NSLOT, H_, B_);
        attn_partial<<<grid, 256, 0, stream>>>(qkvb, po, pl);
    }
    // 2b) combine + normalize
    {
        dim3 grid(W_ / 64, H_, B_);
        attn_combine<<<grid, 256, 0, stream>>>(po, pl, aob);
    }

    // 3) Output projection (bf16 MFMA, fp32 out): out = aob @ wpb^T
    {
        dim3 grid(M_ / 128, C_ / 128);
        gemm_nt_mfma<float><<<grid, 256, 0, stream>>>(aob, wpb, out, C_, C_);
    }
}